// Round 1
// baseline (182.378 us; speedup 1.0000x reference)
//
#include <hip/hip_runtime.h>

// FD_discretizer on fixed 1024x1024 grid, Ex=Ey=1026 extended grid.
// Round 7 (prev): LDS-staged stencil, 10x66 halo, 16 SoA planes, 42.2 KB LDS,
//   3 blocks/CU. Edge frame handled by 24 dedicated slow blocks.
// Round 8 (this): occupancy + L2-locality polish.
//   - Tile 8x62, halo 10x64 (NNODE=640): LDS = 16*640*4 = 40960 B exactly ->
//     4 blocks/CU (160 KB exact), __launch_bounds__(256,4) caps VGPR<=128
//     (16 waves/CU vs 12 before). Halo row stride is now a shift, not /66.
//   - XCD-aware bijective swizzle, column-major within each XCD band:
//     vertically adjacent tiles (which share 2 full halo rows ~20% of reads)
//     run consecutively on the SAME XCD -> halo rows hit that XCD's L2.
//   - Arithmetic bit-identical to round 7 (absmax already at threshold).

#define NXC 1024               // NX == NY
#define EXC 1026               // Ex == Ey
#define NN  (NXC*NXC)

#define TB_ROWS 8
#define TB_COLS 62
#define H_ROWS  10             // TB_ROWS + 2
#define H_COLS  64             // TB_COLS + 2  (power of 2: shift/mask indexing)
#define NNODE   (H_ROWS*H_COLS)   // 640

#define N_CT 17                // col tiles: ceil(1020/62)
#define N_RT 128               // row tiles
#define N_FAST (N_CT*N_RT)     // 2176
#define TILES_PER_XCD (N_FAST/8)  // 272

enum { T_NORMAL=0, T_INFLOW=4, T_OUTFLOW=5, T_WALL=6, T_PRESS=7 };

struct V3 { float u,v,p; };

__device__ __forceinline__ int ntype(int io,int jo){
  if (io==NXC-1) return T_OUTFLOW;
  if (io==0)     return T_INFLOW;
  if (jo==0 || jo==NXC-1) return T_WALL;
  return T_NORMAL;
}

// BC-enforced extended field value at extended coords (je,ie) in [0,1025]^2.
template<bool NEWF>
__device__ __forceinline__ V3 ext_at(int je,int ie,
    const float* __restrict__ uvp,
    const float* __restrict__ node_y)
{
  V3 r;
  const bool bl=(ie==0), br=(ie==EXC-1), bb=(je==0), bt=(je==EXC-1);
  const bool onx = bl||br, ony = bb||bt;
  const bool ghost = (onx && !ony) || (ony && !onx);   // ring minus corners
  if (!ghost){
    int io = ie-1; io = io<0?0:(io>NXC-1?NXC-1:io);
    int jo = je-1; jo = jo<0?0:(jo>NXC-1?NXC-1:jo);
    int m3 = 3*(jo*NXC+io);
    r.u = uvp[m3]; r.v = uvp[m3+1]; r.p = uvp[m3+2];
    if (NEWF && je==EXC/2 && ie==EXC/2) r.p = 0.f;     // PRESS_POINT
    return r;
  }
  int dje=0, die=0, gt;
  if (bl)      { die= 1; gt=T_INFLOW;  }
  else if (br) { die=-1; gt=T_OUTFLOW; }
  else if (bb) { dje= 1; gt=T_WALL;    }
  else         { dje=-1; gt=T_WALL;    }
  int io1 = ie+die-1, jo1 = je+dje-1;
  int m1 = 3*(jo1*NXC+io1);
  int m2 = 3*((jo1+dje)*NXC + (io1+die));
  float u2=uvp[m2], v2=uvp[m2+1], p2=uvp[m2+2];
  int nt1 = ntype(io1,jo1);
  if (gt==T_OUTFLOW){
    float p1 = (nt1==T_OUTFLOW) ? 0.f : uvp[m1+2];
    r.u=u2; r.v=v2; r.p = 2.f*p1 - p2;
  } else {
    float du,dv;
    if (nt1==T_INFLOW || nt1==T_WALL){ du=node_y[m1]; dv=node_y[m1+1]; }
    else                             { du=uvp[m1];    dv=uvp[m1+1];    }
    r.u = 2.f*du - u2; r.v = 2.f*dv - v2; r.p = p2;
  }
  return r;
}

// full slow-path computation for one output node (round-2-verified)
__device__ void process_slow(int io,int jo,
    const float* __restrict__ uvp, const float* __restrict__ uvo,
    const float* __restrict__ ndy, const float* __restrict__ ebm,
    float dt,float uc,float cc,float convc,float pc,float dc,float relax,
    float* __restrict__ out)
{
  const int o = jo*NXC + io;
  const int ie0 = io+1, je0 = jo+1;
  V3 C  = ext_at<true >(je0,  ie0,  uvp, ndy);
  V3 W  = ext_at<true >(je0,  ie0-1,uvp, ndy);
  V3 E  = ext_at<true >(je0,  ie0+1,uvp, ndy);
  V3 S  = ext_at<true >(je0-1,ie0,  uvp, ndy);
  V3 Nn = ext_at<true >(je0+1,ie0,  uvp, ndy);
  V3 SW = ext_at<true >(je0-1,ie0-1,uvp, ndy);
  V3 SE = ext_at<true >(je0-1,ie0+1,uvp, ndy);
  V3 NW = ext_at<true >(je0+1,ie0-1,uvp, ndy);
  V3 NE = ext_at<true >(je0+1,ie0+1,uvp, ndy);
  V3 Co = ext_at<false>(je0,  ie0,  uvo, ndy);
  V3 Wo = ext_at<false>(je0,  ie0-1,uvo, ndy);
  V3 Eo = ext_at<false>(je0,  ie0+1,uvo, ndy);
  V3 So = ext_at<false>(je0-1,ie0,  uvo, ndy);
  V3 No = ext_at<false>(je0+1,ie0,  uvo, ndy);

  const int eC = je0*EXC+ie0;
  const int eW = eC-1, eE = eC+1, eS = eC-EXC, eN = eC+EXC;
  float dxxC=ebm[5*eC+0], dxyC=ebm[5*eC+1], dexC=ebm[5*eC+2],
        deyC=ebm[5*eC+3], JmC=ebm[5*eC+4];
  float dxxW=ebm[5*eW+0], dxyW=ebm[5*eW+1], JmW=ebm[5*eW+4];
  float dxxE=ebm[5*eE+0], dxyE=ebm[5*eE+1], JmE=ebm[5*eE+4];
  float dexS=ebm[5*eS+2], deyS=ebm[5*eS+3], JmS=ebm[5*eS+4];
  float dexN=ebm[5*eN+2], deyN=ebm[5*eN+3], JmN=ebm[5*eN+4];
  const float rC=1.f/JmC, rW=1.f/JmW, rE=1.f/JmE, rS=1.f/JmS, rN=1.f/JmN;

  float UC=(C.u*dxxC + C.v*dxyC)*rC, UW=(W.u*dxxW + W.v*dxyW)*rW, UE=(E.u*dxxE + E.v*dxyE)*rE;
  float VC=(C.u*dexC + C.v*deyC)*rC, VS=(S.u*dexS + S.v*deyS)*rS, VN=(Nn.u*dexN + Nn.v*deyN)*rN;
  float UCo=(Co.u*dxxC + Co.v*dxyC)*rC, UWo=(Wo.u*dxxW + Wo.v*dxyW)*rW, UEo=(Eo.u*dxxE + Eo.v*dxyE)*rE;
  float VCo=(Co.u*dexC + Co.v*deyC)*rC, VSo=(So.u*dexS + So.v*deyS)*rS, VNo=(No.u*dexN + No.v*deyN)*rN;

  float Ufl =0.5f*(UW +UC ), Ufr =0.5f*(UC +UE );
  float Vfd =0.5f*(VS +VC ), Vfu =0.5f*(VC +VN );
  float Uflo=0.5f*(UWo+UCo), Ufro=0.5f*(UCo+UEo);
  float Vfdo=0.5f*(VSo+VCo), Vfuo=0.5f*(VCo+VNo);

  const float loss = (Ufr - Ufl + Vfu - Vfd) * cc;

  float cnu = 0.5f*(C.u+E.u)*Ufr - 0.5f*(W.u+C.u)*Ufl + 0.5f*(C.u+Nn.u)*Vfu - 0.5f*(S.u+C.u)*Vfd;
  float cnv = 0.5f*(C.v+E.v)*Ufr - 0.5f*(W.v+C.v)*Ufl + 0.5f*(C.v+Nn.v)*Vfu - 0.5f*(S.v+C.v)*Vfd;
  float cou = 0.5f*(Co.u+Eo.u)*Ufro - 0.5f*(Wo.u+Co.u)*Uflo + 0.5f*(Co.u+No.u)*Vfuo - 0.5f*(So.u+Co.u)*Vfdo;
  float cov = 0.5f*(Co.v+Eo.v)*Ufro - 0.5f*(Wo.v+Co.v)*Uflo + 0.5f*(Co.v+No.v)*Vfuo - 0.5f*(So.v+Co.v)*Vfdo;
  const float convu = relax*cou + (1.f-relax)*cnu;
  const float convv = relax*cov + (1.f-relax)*cnv;

  float a11C=(dxxC*dxxC+dxyC*dxyC)*rC, a11W=(dxxW*dxxW+dxyW*dxyW)*rW, a11E=(dxxE*dxxE+dxyE*dxyE)*rE;
  float a22C=(dexC*dexC+deyC*deyC)*rC, a22S=(dexS*dexS+deyS*deyS)*rS, a22N=(dexN*dexN+deyN*deyN)*rN;
  float du = 0.5f*(a11C+a11E)*(E.u -C.u) - 0.5f*(a11W+a11C)*(C.u-W.u)
           + 0.5f*(a22C+a22N)*(Nn.u-C.u) - 0.5f*(a22S+a22C)*(C.u-S.u);
  float dv = 0.5f*(a11C+a11E)*(E.v -C.v) - 0.5f*(a11W+a11C)*(C.v-W.v)
           + 0.5f*(a22C+a22N)*(Nn.v-C.v) - 0.5f*(a22S+a22C)*(C.v-S.v);

  float pqW=W.p*rW, pqE=E.p*rE, pqS=S.p*rS, pqN=Nn.p*rN;
  const float gPx = 0.5f*(pqE*dxxE - pqW*dxxW) + 0.5f*(pqN*dexN - pqS*dexS);
  const float gPy = 0.5f*(pqN*deyN - pqS*deyS) + 0.5f*(pqE*dxyE - pqW*dxyW);

  const float rdt = 1.f/dt;
  const float unst_u = (C.u - Co.u)*rdt*rC;
  const float unst_v = (C.v - Co.v)*rdt*rC;

  const float momu = uc*unst_u + convc*convu + pc*gPx - dc*du;
  const float momv = uc*unst_v + convc*convv + pc*gPy - dc*dv;

  const float visu = (SW.u+SE.u+NW.u+NE.u + 2.f*(S.u+W.u+E.u+Nn.u) + 4.f*C.u)*0.0625f;
  const float visv = (SW.v+SE.v+NW.v+NE.v + 2.f*(S.v+W.v+E.v+Nn.v) + 4.f*C.v)*0.0625f;
  const float visp = (SW.p+SE.p+NW.p+NE.p + 2.f*(S.p+W.p+E.p+Nn.p) + 4.f*C.p)*0.0625f;

  out[o]        = loss;
  out[NN + o]   = momu;
  out[2*NN + o] = momv;
  const int vb = 3*NN + 3*o;
  out[vb]   = visu;
  out[vb+1] = visv;
  out[vb+2] = visp;
}

#define NEDGE_BLK 24

// LDS plane ids
#define P_U   0
#define P_V   1
#define P_P   2
#define P_UO  3
#define P_VO  4
#define P_CU  5     // contravariant U (new)
#define P_CV  6     // contravariant V (new)
#define P_CUO 7
#define P_CVO 8
#define P_A11 9
#define P_A22 10
#define P_PQX 11
#define P_PQY 12
#define P_PEX 13
#define P_PEY 14
#define P_RJ  15

extern "C" __global__ void __launch_bounds__(256, 4)
fd_kernel(const float* __restrict__ uvp,     // original_uv  n x 3
          const float* __restrict__ uvo,     // uv_old       n x 3
          const float* __restrict__ ndy,     // node_y       n x 3
          const float* __restrict__ ebm,     // ext metrics  n_ext x 5
          const float* __restrict__ dtg,     // dt           1
          const float* __restrict__ th,      // pde_theta    5
          const float* __restrict__ rl,      // relaxation   1
          float* __restrict__ out)
{
  const int bid = blockIdx.x;
  const int tid = threadIdx.x;

  const float dt   = dtg[0];
  const float uc   = th[0], cc = th[1], convc = th[2], pc = th[3], dc = th[4];
  const float relax= rl[0];
  const float rdt  = 1.f/dt;

  if (bid < NEDGE_BLK){
    // boundary frame: jo in {0,1023} all io, plus io in {0,1,1022,1023}
    // for jo in [1,1022]. 6136 nodes, 1 node/thread.
    const int t = bid*256 + tid;
    if (t >= 6136) return;
    int io, jo;
    if (t < 2048){ jo = (t < 1024) ? 0 : 1023; io = t & 1023; }
    else { int u = t - 2048; jo = 1 + (u >> 2); int c = u & 3; io = (c < 2) ? c : 1020 + c; }
    process_slow(io, jo, uvp,uvo,ndy,ebm, dt,uc,cc,convc,pc,dc,relax, out);
    return;
  }

  // ---------------- fast path: LDS-staged 8x62 output tile -----------------
  __shared__ float sm[16][NNODE];            // 16 SoA planes, 40960 B exactly

  // XCD-aware bijective swizzle: HW round-robins bid -> XCD (bid & 7, and
  // NEDGE_BLK=24 is a multiple of 8 so fast blocks stay aligned). Give each
  // XCD a contiguous band of 272 tiles ordered column-major (rt fastest) so
  // consecutive same-XCD blocks are VERTICAL neighbors sharing 2 halo rows
  // (~20% of reads) -> served from that XCD's L2.
  const int f   = bid - NEDGE_BLK;
  const int xcd = f & 7;
  const int s   = f >> 3;
  const int t   = xcd*TILES_PER_XCD + s;     // [0, 2176)
  const int ct  = t >> 7;                    // t / 128  -> col tile 0..16
  const int rt  = t & 127;                   //          -> row tile 0..127
  int X0  = 2 + ct*TB_COLS;  if (X0  > 960)  X0  = 960;   // cols X0..X0+61 in [2,1021]
  int jo0 = 1 + rt*TB_ROWS;  if (jo0 > 1015) jo0 = 1015;  // rows jo0..jo0+7 in [1,1022]

  // ---- phase 1: stage 10x64 halo nodes, derived quantities computed once ----
  #pragma unroll
  for (int it=0; it<3; ++it){
    const int idx = tid + it*256;
    if (idx < NNODE){
      const int r  = idx >> 6;               // / H_COLS
      const int c  = idx & 63;
      const int jo = jo0 - 1 + r;            // interior row in [0,1023]
      const int io = X0  - 1 + c;            // interior col in [1,1022]
      const int g3 = 3*(jo*NXC + io);
      float u = uvp[g3], v = uvp[g3+1], p = uvp[g3+2];
      if (jo==512 && io==512) p = 0.f;       // PRESS_POINT (new field only)
      const float uo = uvo[g3], vo = uvo[g3+1];
      const int e5 = 5*((jo+1)*EXC + io + 1);
      const float dxx=ebm[e5], dxy=ebm[e5+1], dex=ebm[e5+2], dey=ebm[e5+3], Jm=ebm[e5+4];
      const float rJ = 1.f/Jm;
      sm[P_U ][idx]=u;  sm[P_V ][idx]=v;  sm[P_P ][idx]=p;
      sm[P_UO][idx]=uo; sm[P_VO][idx]=vo;
      sm[P_CU ][idx]=(u *dxx + v *dxy)*rJ;
      sm[P_CV ][idx]=(u *dex + v *dey)*rJ;
      sm[P_CUO][idx]=(uo*dxx + vo*dxy)*rJ;
      sm[P_CVO][idx]=(uo*dex + vo*dey)*rJ;
      sm[P_A11][idx]=(dxx*dxx + dxy*dxy)*rJ;
      sm[P_A22][idx]=(dex*dex + dey*dey)*rJ;
      const float pq = p*rJ;
      sm[P_PQX][idx]=pq*dxx; sm[P_PQY][idx]=pq*dxy;
      sm[P_PEX][idx]=pq*dex; sm[P_PEY][idx]=pq*dey;
      sm[P_RJ ][idx]=rJ;
    }
  }
  __syncthreads();

  // ---- phase 2: 2 outputs per thread, all reads from LDS ----
  const int tx = tid & 63, ty = tid >> 6;
  if (tx < TB_COLS){
    #pragma unroll
    for (int kk=0; kk<2; ++kk){
      const int r = 1 + ty*2 + kk;           // local halo row of center
      const int c = 1 + tx;                  // local halo col of center
      const int iC = r*H_COLS + c;
      const int iW = iC-1, iE = iC+1, iS = iC-H_COLS, iN = iC+H_COLS;

      const float UC=sm[P_CU][iC], UW=sm[P_CU][iW], UE=sm[P_CU][iE];
      const float VC=sm[P_CV][iC], VS=sm[P_CV][iS], VN=sm[P_CV][iN];
      const float UCo=sm[P_CUO][iC], UWo=sm[P_CUO][iW], UEo=sm[P_CUO][iE];
      const float VCo=sm[P_CVO][iC], VSo=sm[P_CVO][iS], VNo=sm[P_CVO][iN];

      const float Ufl =0.5f*(UW +UC ), Ufr =0.5f*(UC +UE );
      const float Vfd =0.5f*(VS +VC ), Vfu =0.5f*(VC +VN );
      const float Uflo=0.5f*(UWo+UCo), Ufro=0.5f*(UCo+UEo);
      const float Vfdo=0.5f*(VSo+VCo), Vfuo=0.5f*(VCo+VNo);

      const float loss = (Ufr - Ufl + Vfu - Vfd) * cc;

      const float u_c=sm[P_U][iC], v_c=sm[P_V][iC];
      const float uW =sm[P_U][iW], vW =sm[P_V][iW];
      const float uE =sm[P_U][iE], vE =sm[P_V][iE];
      const float uS =sm[P_U][iS], vS =sm[P_V][iS];
      const float uN =sm[P_U][iN], vN =sm[P_V][iN];

      const float cnu = 0.5f*(u_c+uE)*Ufr - 0.5f*(uW+u_c)*Ufl
                      + 0.5f*(u_c+uN)*Vfu - 0.5f*(uS+u_c)*Vfd;
      const float cnv = 0.5f*(v_c+vE)*Ufr - 0.5f*(vW+v_c)*Ufl
                      + 0.5f*(v_c+vN)*Vfu - 0.5f*(vS+v_c)*Vfd;

      const float uoc=sm[P_UO][iC], voc=sm[P_VO][iC];
      const float uoW=sm[P_UO][iW], voW=sm[P_VO][iW];
      const float uoE=sm[P_UO][iE], voE=sm[P_VO][iE];
      const float uoS=sm[P_UO][iS], voS=sm[P_VO][iS];
      const float uoN=sm[P_UO][iN], voN=sm[P_VO][iN];

      const float cou = 0.5f*(uoc+uoE)*Ufro - 0.5f*(uoW+uoc)*Uflo
                      + 0.5f*(uoc+uoN)*Vfuo - 0.5f*(uoS+uoc)*Vfdo;
      const float cov = 0.5f*(voc+voE)*Ufro - 0.5f*(voW+voc)*Uflo
                      + 0.5f*(voc+voN)*Vfuo - 0.5f*(voS+voc)*Vfdo;

      const float convu = relax*cou + (1.f-relax)*cnu;
      const float convv = relax*cov + (1.f-relax)*cnv;

      const float a11C=sm[P_A11][iC], a11W=sm[P_A11][iW], a11E=sm[P_A11][iE];
      const float a22C=sm[P_A22][iC], a22S=sm[P_A22][iS], a22N=sm[P_A22][iN];
      const float du = 0.5f*(a11C+a11E)*(uE-u_c) - 0.5f*(a11W+a11C)*(u_c-uW)
                     + 0.5f*(a22C+a22N)*(uN-u_c) - 0.5f*(a22S+a22C)*(u_c-uS);
      const float dv = 0.5f*(a11C+a11E)*(vE-v_c) - 0.5f*(a11W+a11C)*(v_c-vW)
                     + 0.5f*(a22C+a22N)*(vN-v_c) - 0.5f*(a22S+a22C)*(v_c-vS);

      const float gPx = 0.5f*(sm[P_PQX][iE]-sm[P_PQX][iW]) + 0.5f*(sm[P_PEX][iN]-sm[P_PEX][iS]);
      const float gPy = 0.5f*(sm[P_PEY][iN]-sm[P_PEY][iS]) + 0.5f*(sm[P_PQY][iE]-sm[P_PQY][iW]);

      const float rJC = sm[P_RJ][iC];
      const float unst_u = (u_c - uoc)*rdt*rJC;
      const float unst_v = (v_c - voc)*rdt*rJC;

      const float momu = uc*unst_u + convc*convu + pc*gPx - dc*du;
      const float momv = uc*unst_v + convc*convv + pc*gPy - dc*dv;

      // vis: [1 2 1; 2 4 2; 1 2 1]/16 over 3x3
      const float uSW=sm[P_U][iS-1], uSE=sm[P_U][iS+1], uNW=sm[P_U][iN-1], uNE=sm[P_U][iN+1];
      const float vSW=sm[P_V][iS-1], vSE=sm[P_V][iS+1], vNW=sm[P_V][iN-1], vNE=sm[P_V][iN+1];
      const float p_c=sm[P_P][iC];
      const float pW=sm[P_P][iW], pE=sm[P_P][iE], pS=sm[P_P][iS], pN=sm[P_P][iN];
      const float pSW=sm[P_P][iS-1], pSE=sm[P_P][iS+1], pNW=sm[P_P][iN-1], pNE=sm[P_P][iN+1];

      const float visu=(uSW+uSE+uNW+uNE + 2.f*(uS+uW+uE+uN) + 4.f*u_c)*0.0625f;
      const float visv=(vSW+vSE+vNW+vNE + 2.f*(vS+vW+vE+vN) + 4.f*v_c)*0.0625f;
      const float visp=(pSW+pSE+pNW+pNE + 2.f*(pS+pW+pE+pN) + 4.f*p_c)*0.0625f;

      const int j = jo0 + ty*2 + kk;
      const int o = j*NXC + X0 + tx;
      out[o]        = loss;
      out[NN + o]   = momu;
      out[2*NN + o] = momv;
      const int vb = 3*NN + 3*o;
      out[vb]   = visu;
      out[vb+1] = visv;
      out[vb+2] = visp;
    }
  }
}

extern "C" void kernel_launch(void* const* d_in, const int* in_sizes, int n_in,
                              void* d_out, int out_size, void* d_ws, size_t ws_size,
                              hipStream_t stream) {
  const float* uvp = (const float*)d_in[0];   // original_uv
  const float* uvo = (const float*)d_in[1];   // uv_old
  const float* ndy = (const float*)d_in[2];   // node_y
  const float* ebm = (const float*)d_in[4];   // extended_block_metrics
  const float* dtg = (const float*)d_in[5];   // dt_graph
  const float* th  = (const float*)d_in[6];   // pde_theta
  const float* rl  = (const float*)d_in[7];   // relaxtion
  float* out = (float*)d_out;

  // 24 edge blocks first (overlap main wave-front) + 17x128 = 2176 fast tiles
  fd_kernel<<<dim3(NEDGE_BLK + N_FAST), dim3(256), 0, stream>>>(uvp, uvo, ndy, ebm, dtg, th, rl, out);
}